// Round 17
// baseline (95.686 us; speedup 1.0000x reference)
//
#include <hip/hip_runtime.h>

#define N2 4096
#define D 128
#define TAU_INV 10.0f
#define E2SCALE 14.4269504088896340736f   // 10 * log2(e): exp(10x) = exp2(x*E2SCALE)
#define BM 128                    // i-rows per block (4 waves x 32) — half super-tile
#define BN 256                    // j-cols per block (8 tiles, LDS-staged)
#define NT (BN / 32)              // 8
#define NIT 16                    // 256-row super-tiles per side
#define NUT (NIT * (NIT + 1) / 2) // 136 upper-triangle super-tiles
#define GEMM_BLOCKS (2 * NUT)     // 272 half-blocks
#define SLOTW 48                  // pse slots/row: [0,16) row-sums, [16,46) col-sums
#define NCLS 10
#define CGRP 16
#define CROWS (N2 / CGRP)         // 256 rows per class block
#define CB (NCLS * CGRP)          // 160 class blocks

typedef __attribute__((ext_vector_type(8))) short bf16x8;
typedef __attribute__((ext_vector_type(16))) float floatx16;

__device__ __forceinline__ short f2bf(float f) {
    unsigned u = __float_as_uint(f);
    u = (u + 0x7fff + ((u >> 16) & 1)) >> 16;   // RNE
    return (short)u;
}
__device__ __forceinline__ float bf2f(short s) {
    return __uint_as_float(((unsigned)(unsigned short)s) << 16);
}

// Normalize rows of p = concat(z_i, z_j) in fp32, emit bf16. Two layouts:
//   qb  [row][d]                  row-major (class-sum path)
//   qb2 [row/32][k/8][row%32][8]  chunk-major (MFMA fragments + LDS staging)
// Zeroes this row's 48 pse slots; block 0 zeroes S/T/CNT.
__global__ __launch_bounds__(64) void prep_kernel(const float* __restrict__ zi,
                                                  const float* __restrict__ zj,
                                                  short* __restrict__ qb,
                                                  short* __restrict__ qb2,
                                                  float* __restrict__ pse,
                                                  float* __restrict__ S) {
    int row = blockIdx.x;
    int lane = threadIdx.x;                    // 64 lanes, 2 floats each
    const float* src = (row < 2048) ? (zi + row * D) : (zj + (row - 2048) * D);
    float2 v = ((const float2*)src)[lane];
    float ss = v.x * v.x + v.y * v.y;
    #pragma unroll
    for (int m = 1; m < 64; m <<= 1) ss += __shfl_xor(ss, m);
    float inv = 1.0f / sqrtf(ss);              // ||p|| ~ sqrt(128) >> eps
    short2 o;
    o.x = f2bf(v.x * inv);
    o.y = f2bf(v.y * inv);
    ((short2*)(qb + row * D))[lane] = o;
    int addr2 = (row >> 5) * 4096 + (lane >> 2) * 256 + (row & 31) * 8 + 2 * (lane & 3);
    *(short2*)(qb2 + addr2) = o;
    if (lane < SLOTW) pse[row * SLOTW + lane] = 0.f;
    if (row == 0)
        for (int k = lane; k < NCLS * D + 2 * NCLS; k += 64) S[k] = 0.f;
}

// Grid = 272 GEMM half-blocks + 160 class blocks, all 256 threads.
//
// Block b<272: super-tile u=b>>1 -> (it,js) upper-tri, half h=b&1 -> i-rows
// [it*256+h*128, +128) x j-cols [js*256, +256). Stages the 64KB B-slice to
// LDS (contiguous in qb2), A per-wave in registers, MFMA 32x32x16 K=128.
// SYMMETRY: row-sums -> pse[row][js]; off-diag col-sums (lane sums its 16 acc
// + shfl_xor(32) + cross-wave LDS add) -> pse[js*256+j][16+2*it+h]. Every
// slot has a unique writer; unwritten slots are zero (prep) -> finish sums
// all 48. Work per block is HALF of r16's; 272+160 blocks spread over the
// 120 CUs that r16 left idle (per-block wall tracks per-block work at a
// universal ~7x stall factor -> makespan drops ~0.55x).
// C/D: col=lane&31, row=(reg&3)+8*(reg>>2)+4*(lane>>5). Diagonal tile
// (j0==rbase, only when it==js) wave-uniform; self-pair excluded as always.
//
// Class block: r6's proven 256-thread masked S/T/CNT sums over 256 rows of
// qb (labels used as VALUES only -> poison-safe).
__global__ __launch_bounds__(256) void main_kernel(const short* __restrict__ qb,
                                                   const short* __restrict__ qb2,
                                                   const long long* __restrict__ y,
                                                   float* __restrict__ pse,
                                                   float* __restrict__ S) {
    int tid = threadIdx.x;
    int wave = tid >> 6;
    int lane = tid & 63;

    if (blockIdx.x >= GEMM_BLOCKS) {
        // ---- class-sum path (256 thr: 2 row-groups x 128 dims) ----
        __shared__ float shS[256];
        __shared__ float shT[4];
        __shared__ float shC[2];
        int cb = blockIdx.x - GEMM_BLOCKS;   // 0..159
        int c  = cb / CGRP;
        int g  = cb % CGRP;
        int d  = tid & 127;
        int rh = tid >> 7;                   // 0/1
        int r0 = g * CROWS + rh * (CROWS / 2);

        float sS = 0.f, sT = 0.f, cnt = 0.f;
        #pragma unroll 4
        for (int i = 0; i < CROWS / 2; ++i) {
            int r = r0 + i;
            bool m = ((int)y[r & 2047] == c);      // wave-uniform broadcast
            float q = bf2f(qb[r * D + d]);         // coalesced reads
            sS += m ? q : 0.f;
            sT += m ? q * q : 0.f;
            cnt += m ? 1.f : 0.f;
        }

        shS[tid] = sS;
        #pragma unroll
        for (int m = 1; m < 64; m <<= 1) sT += __shfl_xor(sT, m);
        if (lane == 0) shT[wave] = sT;
        if (d == 0) shC[rh] = cnt;
        __syncthreads();
        if (tid < 128) atomicAdd(&S[c * D + tid], shS[tid] + shS[tid + 128]);
        if (tid == 0) {
            atomicAdd(&S[NCLS * D + c], shT[0] + shT[1] + shT[2] + shT[3]);   // T_c
            atomicAdd(&S[NCLS * D + NCLS + c], shC[0] + shC[1]);              // CNT_c
        }
        return;
    }

    // ---- GEMM path: b -> (it, js, h) ----
    __shared__ short ldsB[BN * D];     // 64 KB
    __shared__ float colsum[BN];       // 1 KB
    int b = blockIdx.x;
    int h = b & 1;
    int u = b >> 1, it = 0;
    while (u >= NIT - it) { u -= NIT - it; ++it; }
    int js = it + u;
    int col  = lane & 31;
    int half = lane >> 5;
    int rbase = it * 256 + h * BM + wave * 32;
    bool offdiag = (it != js);

    // stage the B-slice: 64KB contiguous in qb2, coalesced copy (16/thread)
    {
        const bf16x8* src = (const bf16x8*)(qb2 + js * (BN * D));
        bf16x8* dst = (bf16x8*)ldsB;
        #pragma unroll
        for (int i = 0; i < 16; ++i) dst[tid + 256 * i] = src[tid + 256 * i];
    }
    colsum[tid] = 0.f;

    // A fragments for this wave's 32 rows: lane-contiguous from qb2
    const short* ap = qb2 + ((rbase >> 5) * 4096) + lane * 8;
    bf16x8 af[8];
    #pragma unroll
    for (int k = 0; k < 8; ++k) af[k] = *(const bf16x8*)(ap + k * 512);

    float se[16];
    #pragma unroll
    for (int r = 0; r < 16; ++r) se[r] = 0.f;

    __syncthreads();                   // B staged, colsum zeroed

    const bf16x8* lb = (const bf16x8*)ldsB;
    #pragma unroll
    for (int t = 0; t < NT; ++t) {
        int j0 = js * BN + t * 32;

        floatx16 acc;
        #pragma unroll
        for (int r = 0; r < 16; ++r) acc[r] = 0.f;
        #pragma unroll
        for (int k = 0; k < 8; ++k)
            acc = __builtin_amdgcn_mfma_f32_32x32x16_bf16(
                af[k], lb[t * 512 + k * 64 + lane], acc, 0, 0, 0);

        if (j0 == rbase) {                    // wave-uniform: diagonal tile
            int jcol = j0 + col;
            #pragma unroll
            for (int r = 0; r < 16; ++r) {
                int rowr = rbase + (r & 3) + 8 * (r >> 2) + 4 * half;
                float e = __builtin_amdgcn_exp2f(acc[r] * E2SCALE);
                se[r] += (rowr == jcol) ? 0.f : e;
            }
        } else {
            float cs = 0.f;
            #pragma unroll
            for (int r = 0; r < 16; ++r) {
                float e = __builtin_amdgcn_exp2f(acc[r] * E2SCALE);
                se[r] += e;
                cs += e;
            }
            if (offdiag) {                    // col-sums for the mirrored tile
                cs += __shfl_xor(cs, 32);     // both halves: full 32-row sum
                if (half == 0) atomicAdd(&colsum[t * 32 + col], cs);
            }
        }
    }

    // row-sums: reduce over 32 cols, plain-store slot js
    #pragma unroll
    for (int r = 0; r < 16; ++r) {
        float a = se[r];
        #pragma unroll
        for (int m = 1; m < 32; m <<= 1) a += __shfl_xor(a, m);
        if (col == 0) {
            int rowr = rbase + (r & 3) + 8 * (r >> 2) + 4 * half;
            pse[rowr * SLOTW + js] = a;       // unique (row, js) writer
        }
    }

    // col-sums: slot 16+2*it+h for js-block rows, plain store
    if (offdiag) {
        __syncthreads();                      // all waves' colsum adds done
        pse[(js * BN + tid) * SLOTW + 16 + 2 * it + h] = colsum[tid];  // unique
    }
}

// loss = (sum_i log(sum_k pse[i][k])  -  sum_c 10*(||S_c||^2 - T_c)/(n_c-1)) / N2
__global__ __launch_bounds__(512) void finish_kernel(const float* __restrict__ pse,
                                                     const float* __restrict__ S,
                                                     float* __restrict__ out) {
    __shared__ float red[16];
    int tid = threadIdx.x;
    int wave = tid >> 6;
    int lane = tid & 63;

    // denominator: sum 48 slots per row (192B contiguous), log, reduce
    float L = 0.f;
    for (int r = tid; r < N2; r += 512) {
        float s = 0.f;
        #pragma unroll
        for (int k = 0; k < SLOTW; ++k) s += pse[r * SLOTW + k];
        L += __logf(s);
    }
    #pragma unroll
    for (int m = 1; m < 64; m <<= 1) L += __shfl_xor(L, m);

    // positive-pair term: wave w handles classes w and w+8
    float P = 0.f;
    for (int c = wave; c < NCLS; c += 8) {
        float2 sv = ((const float2*)(S + c * D))[lane];
        float s2 = sv.x * sv.x + sv.y * sv.y;
        #pragma unroll
        for (int m = 1; m < 64; m <<= 1) s2 += __shfl_xor(s2, m);
        float n = S[NCLS * D + NCLS + c];
        P += (n >= 2.0f) ? (s2 - S[NCLS * D + c]) * TAU_INV / (n - 1.0f) : 0.f;
    }

    if (lane == 0) { red[wave] = L; red[8 + wave] = P; }
    __syncthreads();
    if (tid == 0) {
        float Ls = 0.f, Ps = 0.f;
        #pragma unroll
        for (int w = 0; w < 8; ++w) { Ls += red[w]; Ps += red[8 + w]; }
        out[0] = (Ls - Ps) * (1.0f / (float)N2);
    }
}

extern "C" void kernel_launch(void* const* d_in, const int* in_sizes, int n_in,
                              void* d_out, int out_size, void* d_ws, size_t ws_size,
                              hipStream_t stream) {
    const float*     zi = (const float*)d_in[0];
    const float*     zj = (const float*)d_in[1];
    const long long* y  = (const long long*)d_in[2];
    float* out = (float*)d_out;

    char* ws = (char*)d_ws;
    short* qb   = (short*)ws;                                  // 1 MB row-major
    short* qb2  = qb + N2 * D;                                 // 1 MB chunk-major
    float* pse  = (float*)(ws + 2 * N2 * D * sizeof(short));   // 4096*48 f32 = 768 KB
    float* S    = pse + N2 * SLOTW;                            // 1300 f32: S/T/CNT

    prep_kernel<<<N2, 64, 0, stream>>>(zi, zj, qb, qb2, pse, S);
    main_kernel<<<GEMM_BLOCKS + CB, 256, 0, stream>>>(qb, qb2, y, pse, S);
    finish_kernel<<<1, 512, 0, stream>>>(pse, S, out);
}

// Round 18
// 92.585 us; speedup vs baseline: 1.0335x; 1.0335x over previous
//
#include <hip/hip_runtime.h>

#define N2 4096
#define D 128
#define TAU_INV 10.0f
#define E2SCALE 14.4269504088896340736f   // 10 * log2(e): exp(10x) = exp2(x*E2SCALE)
#define BM 256                    // i-rows per block (8 waves x 32)
#define BN 256                    // j-cols per block (8 tiles, LDS-staged)
#define NT (BN / 32)              // 8
#define NIT (N2 / BM)             // 16
#define GEMM_BLOCKS (NIT * (NIT + 1) / 2)   // 136: only tiles it <= js (symmetry)
#define NCLS 10
#define CGRP 12                   // groups per class -> 120 class blocks
#define CB (NCLS * CGRP)          // 120: grid = 136 + 120 = 256 = ONE round
typedef __attribute__((ext_vector_type(8))) short bf16x8;
typedef __attribute__((ext_vector_type(16))) float floatx16;

__device__ __forceinline__ short f2bf(float f) {
    unsigned u = __float_as_uint(f);
    u = (u + 0x7fff + ((u >> 16) & 1)) >> 16;   // RNE
    return (short)u;
}
__device__ __forceinline__ float bf2f(short s) {
    return __uint_as_float(((unsigned)(unsigned short)s) << 16);
}

// Normalize rows of p = concat(z_i, z_j) in fp32, emit bf16. Two layouts:
//   qb  [row][d]                  row-major (class-sum path)
//   qb2 [row/32][k/8][row%32][8]  chunk-major (MFMA fragments + LDS staging)
// Block 0 zeroes S/T/CNT (class accumulators).
__global__ __launch_bounds__(64) void prep_kernel(const float* __restrict__ zi,
                                                  const float* __restrict__ zj,
                                                  short* __restrict__ qb,
                                                  short* __restrict__ qb2,
                                                  float* __restrict__ S) {
    int row = blockIdx.x;
    int lane = threadIdx.x;                    // 64 lanes, 2 floats each
    const float* src = (row < 2048) ? (zi + row * D) : (zj + (row - 2048) * D);
    float2 v = ((const float2*)src)[lane];
    float ss = v.x * v.x + v.y * v.y;
    #pragma unroll
    for (int m = 1; m < 64; m <<= 1) ss += __shfl_xor(ss, m);
    float inv = 1.0f / sqrtf(ss);              // ||p|| ~ sqrt(128) >> eps
    short2 o;
    o.x = f2bf(v.x * inv);
    o.y = f2bf(v.y * inv);
    ((short2*)(qb + row * D))[lane] = o;
    int addr2 = (row >> 5) * 4096 + (lane >> 2) * 256 + (row & 31) * 8 + 2 * (lane & 3);
    *(short2*)(qb2 + addr2) = o;
    if (row == 0)
        for (int k = lane; k < NCLS * D + 2 * NCLS; k += 64) S[k] = 0.f;
}

// Grid = 136 GEMM blocks (upper-triangle super-tiles) + 120 class blocks
// = 256 total: EXACTLY one scheduling round (r16's 296 blocks left a 40-block
// second round — the only structural residual in the best config).
//
// GEMM block (it,js): computes its 256x256 tile once; SYMMETRY gives both
// halves: row-sums -> pse[row][js], off-diag col-sums (in-register + LDS
// cross-wave accumulate) -> pse[js*256+j][16+it]... stored via slot it with
// unique writers; unwritten slots untouched but every (row,slot<16) pair is
// written by exactly one block (k<J from col-sums of (k,J), k>=J from
// row-sums of (J,k)) -> plain stores, no atomics, no zero-init needed.
// B-slice staged to LDS (64KB contiguous in qb2); A per-wave in registers;
// MFMA 32x32x16 K=128. C/D: col=lane&31, row=(reg&3)+8*(reg>>2)+4*(lane>>5).
// Diagonal tile (j0==rbase, only when it==js) wave-uniform; self excluded.
//
// Class block (c, g of 12): masked S/T/CNT sums over rows [g*N2/12,(g+1)*N2/12)
// of qb, 4 strided row-groups. Labels used as VALUES only -> poison-safe.
__global__ __launch_bounds__(512) void main_kernel(const short* __restrict__ qb,
                                                   const short* __restrict__ qb2,
                                                   const long long* __restrict__ y,
                                                   float* __restrict__ pse,
                                                   float* __restrict__ S) {
    int tid = threadIdx.x;
    int wave = tid >> 6;
    int lane = tid & 63;

    if (blockIdx.x >= GEMM_BLOCKS) {
        // ---- class-sum path (512 threads: 4 strided row-groups x 128 dims) ----
        __shared__ float shS[512];
        __shared__ float shT[8];
        __shared__ float shC[4];
        int cb = blockIdx.x - GEMM_BLOCKS;   // 0..119
        int c  = cb / CGRP;                  // 0..9
        int g  = cb % CGRP;                  // 0..11
        int d  = tid & 127;
        int rg = tid >> 7;                   // 0..3
        int r0 = (g * N2) / CGRP;
        int r1 = ((g + 1) * N2) / CGRP;

        float sS = 0.f, sT = 0.f, cnt = 0.f;
        for (int r = r0 + rg; r < r1; r += 4) {
            bool m = ((int)y[r & 2047] == c);      // wave-uniform broadcast
            float q = bf2f(qb[r * D + d]);         // coalesced reads
            sS += m ? q : 0.f;
            sT += m ? q * q : 0.f;
            cnt += m ? 1.f : 0.f;
        }

        shS[tid] = sS;
        #pragma unroll
        for (int m = 1; m < 64; m <<= 1) sT += __shfl_xor(sT, m);
        if (lane == 0) shT[wave] = sT;
        if (d == 0) shC[rg] = cnt;
        __syncthreads();
        if (tid < 128)
            atomicAdd(&S[c * D + tid],
                      shS[tid] + shS[tid + 128] + shS[tid + 256] + shS[tid + 384]);
        if (tid == 0) {
            float t8 = 0.f;
            #pragma unroll
            for (int w = 0; w < 8; ++w) t8 += shT[w];
            atomicAdd(&S[NCLS * D + c], t8);                                  // T_c
            atomicAdd(&S[NCLS * D + NCLS + c], shC[0] + shC[1] + shC[2] + shC[3]); // CNT_c
        }
        return;
    }

    // ---- GEMM path: map linear block id -> upper-triangle (it, js) ----
    __shared__ short ldsB[BN * D];     // 64 KB
    __shared__ float colsum[BN];       // 1 KB (off-diag col-sums)
    int b = blockIdx.x, it = 0;
    while (b >= NIT - it) { b -= NIT - it; ++it; }
    int js = it + b;
    int col  = lane & 31;
    int half = lane >> 5;
    int rbase = it * BM + wave * 32;
    bool offdiag = (it != js);

    // stage the B-slice: 64KB contiguous in qb2, coalesced copy
    {
        const bf16x8* src = (const bf16x8*)(qb2 + js * (BN * D));
        bf16x8* dst = (bf16x8*)ldsB;
        #pragma unroll
        for (int i = 0; i < 8; ++i) dst[tid + 512 * i] = src[tid + 512 * i];
    }
    if (tid < BN) colsum[tid] = 0.f;

    // A fragments for this wave's 32 rows: lane-contiguous from qb2
    const short* ap = qb2 + ((rbase >> 5) * 4096) + lane * 8;
    bf16x8 af[8];
    #pragma unroll
    for (int k = 0; k < 8; ++k) af[k] = *(const bf16x8*)(ap + k * 512);

    float se[16];
    #pragma unroll
    for (int r = 0; r < 16; ++r) se[r] = 0.f;

    __syncthreads();                   // B staged, colsum zeroed

    const bf16x8* lb = (const bf16x8*)ldsB;
    #pragma unroll
    for (int t = 0; t < NT; ++t) {
        int j0 = js * BN + t * 32;

        floatx16 acc;
        #pragma unroll
        for (int r = 0; r < 16; ++r) acc[r] = 0.f;
        #pragma unroll
        for (int k = 0; k < 8; ++k)
            acc = __builtin_amdgcn_mfma_f32_32x32x16_bf16(
                af[k], lb[t * 512 + k * 64 + lane], acc, 0, 0, 0);

        if (j0 == rbase) {                    // wave-uniform: diagonal tile
            int jcol = j0 + col;
            #pragma unroll
            for (int r = 0; r < 16; ++r) {
                int rowr = rbase + (r & 3) + 8 * (r >> 2) + 4 * half;
                float e = __builtin_amdgcn_exp2f(acc[r] * E2SCALE);
                se[r] += (rowr == jcol) ? 0.f : e;
            }
        } else {
            float cs = 0.f;
            #pragma unroll
            for (int r = 0; r < 16; ++r) {
                float e = __builtin_amdgcn_exp2f(acc[r] * E2SCALE);
                se[r] += e;
                cs += e;
            }
            if (offdiag) {                    // col-sums for the mirrored tile
                cs += __shfl_xor(cs, 32);     // both halves: full 32-row sum
                if (half == 0) atomicAdd(&colsum[t * 32 + col], cs);
            }
        }
    }

    // row-sums: reduce over 32 cols, plain-store slice js for it-block rows
    #pragma unroll
    for (int r = 0; r < 16; ++r) {
        float a = se[r];
        #pragma unroll
        for (int m = 1; m < 32; m <<= 1) a += __shfl_xor(a, m);
        if (col == 0) {
            int rowr = rbase + (r & 3) + 8 * (r >> 2) + 4 * half;
            pse[rowr * NIT + js] = a;         // unique (row, js) writer
        }
    }

    // col-sums: slice it for js-block rows (mirrored half), plain store
    if (offdiag) {
        __syncthreads();                      // all waves' colsum adds done
        if (tid < BN)
            pse[(js * BN + tid) * NIT + it] = colsum[tid];   // unique writer
    }
}

// loss = (sum_i log(sum_k pse[i][k])  -  sum_c 10*(||S_c||^2 - T_c)/(n_c-1)) / N2
__global__ __launch_bounds__(512) void finish_kernel(const float* __restrict__ pse,
                                                     const float* __restrict__ S,
                                                     float* __restrict__ out) {
    __shared__ float red[16];
    int tid = threadIdx.x;
    int wave = tid >> 6;
    int lane = tid & 63;

    // denominator: sum 16 slice-partials per row (64B contiguous), log, reduce
    float L = 0.f;
    for (int r = tid; r < N2; r += 512) {
        float s = 0.f;
        #pragma unroll
        for (int k = 0; k < NIT; ++k) s += pse[r * NIT + k];
        L += __logf(s);
    }
    #pragma unroll
    for (int m = 1; m < 64; m <<= 1) L += __shfl_xor(L, m);

    // positive-pair term: wave w handles classes w and w+8
    float P = 0.f;
    for (int c = wave; c < NCLS; c += 8) {
        float2 sv = ((const float2*)(S + c * D))[lane];
        float s2 = sv.x * sv.x + sv.y * sv.y;
        #pragma unroll
        for (int m = 1; m < 64; m <<= 1) s2 += __shfl_xor(s2, m);
        float n = S[NCLS * D + NCLS + c];
        P += (n >= 2.0f) ? (s2 - S[NCLS * D + c]) * TAU_INV / (n - 1.0f) : 0.f;
    }

    if (lane == 0) { red[wave] = L; red[8 + wave] = P; }
    __syncthreads();
    if (tid == 0) {
        float Ls = 0.f, Ps = 0.f;
        #pragma unroll
        for (int w = 0; w < 8; ++w) { Ls += red[w]; Ps += red[8 + w]; }
        out[0] = (Ls - Ps) * (1.0f / (float)N2);
    }
}

extern "C" void kernel_launch(void* const* d_in, const int* in_sizes, int n_in,
                              void* d_out, int out_size, void* d_ws, size_t ws_size,
                              hipStream_t stream) {
    const float*     zi = (const float*)d_in[0];
    const float*     zj = (const float*)d_in[1];
    const long long* y  = (const long long*)d_in[2];
    float* out = (float*)d_out;

    char* ws = (char*)d_ws;
    short* qb   = (short*)ws;                                  // 1 MB row-major
    short* qb2  = qb + N2 * D;                                 // 1 MB chunk-major
    float* pse  = (float*)(ws + 2 * N2 * D * sizeof(short));   // 4096*16 f32 = 256 KB
    float* S    = pse + N2 * NIT;                              // 1300 f32: S/T/CNT

    prep_kernel<<<N2, 64, 0, stream>>>(zi, zj, qb, qb2, S);
    main_kernel<<<GEMM_BLOCKS + CB, 512, 0, stream>>>(qb, qb2, y, pse, S);
    finish_kernel<<<1, 512, 0, stream>>>(pse, S, out);
}

// Round 19
// 83.533 us; speedup vs baseline: 1.1455x; 1.1084x over previous
//
#include <hip/hip_runtime.h>

#define N2 4096
#define D 128
#define TAU_INV 10.0f
#define E2SCALE 14.4269504088896340736f   // 10 * log2(e): exp(10x) = exp2(x*E2SCALE)
#define BM 256                    // i-rows per block (8 waves x 32)
#define BN 256                    // j-cols per block (8 tiles, LDS-staged)
#define NT (BN / 32)              // 8
#define NIT (N2 / BM)             // 16
#define GEMM_BLOCKS (NIT * (NIT + 1) / 2)   // 136: only tiles it <= js (symmetry!)
#define NCLS 10
#define CGRP 16
#define CROWS (N2 / CGRP)         // 256 rows per class block
#define CB (NCLS * CGRP)          // 160 class blocks

typedef __attribute__((ext_vector_type(8))) short bf16x8;
typedef __attribute__((ext_vector_type(16))) float floatx16;

__device__ __forceinline__ short f2bf(float f) {
    unsigned u = __float_as_uint(f);
    u = (u + 0x7fff + ((u >> 16) & 1)) >> 16;   // RNE
    return (short)u;
}
__device__ __forceinline__ float bf2f(short s) {
    return __uint_as_float(((unsigned)(unsigned short)s) << 16);
}

// Normalize rows of p = concat(z_i, z_j) in fp32, emit bf16. Two layouts:
//   qb  [row][d]                  row-major (class-sum path)
//   qb2 [row/32][k/8][row%32][8]  chunk-major (MFMA fragments + LDS staging)
// Block 0 zeroes S/T/CNT (class accumulators).
__global__ __launch_bounds__(64) void prep_kernel(const float* __restrict__ zi,
                                                  const float* __restrict__ zj,
                                                  short* __restrict__ qb,
                                                  short* __restrict__ qb2,
                                                  float* __restrict__ S) {
    int row = blockIdx.x;
    int lane = threadIdx.x;                    // 64 lanes, 2 floats each
    const float* src = (row < 2048) ? (zi + row * D) : (zj + (row - 2048) * D);
    float2 v = ((const float2*)src)[lane];
    float ss = v.x * v.x + v.y * v.y;
    #pragma unroll
    for (int m = 1; m < 64; m <<= 1) ss += __shfl_xor(ss, m);
    float inv = 1.0f / sqrtf(ss);              // ||p|| ~ sqrt(128) >> eps
    short2 o;
    o.x = f2bf(v.x * inv);
    o.y = f2bf(v.y * inv);
    ((short2*)(qb + row * D))[lane] = o;
    int addr2 = (row >> 5) * 4096 + (lane >> 2) * 256 + (row & 31) * 8 + 2 * (lane & 3);
    *(short2*)(qb2 + addr2) = o;
    if (row == 0)
        for (int k = lane; k < NCLS * D + 2 * NCLS; k += 64) S[k] = 0.f;
}

// Grid = 136 GEMM blocks (upper-triangle tiles, it<=js) + 160 class blocks.
//
// SYMMETRY: s_ij = s_ji, so block (it,js) computes its 256x256 tile ONCE and
// produces BOTH halves of the exp-sum: row-sums (reduce over cols) -> slice js
// of rows in it-block, AND (off-diag only) col-sums (reduce over rows) ->
// slice it of rows in js-block. Col-sum is cheap: lane sums its 16 acc regs
// in-register + shfl_xor(32) + cross-wave LDS accumulate. pse[row][slice] has
// exactly one writer per slot (k<J from block (k,J) col-sums; k>=J from block
// (J,k) row-sums) -> plain stores, no atomics, no zero-init. GEMM+exp work
// HALVES vs the full-matrix version (256 -> 136 tile-blocks).
// B-slice staged to LDS from qb2 (64KB contiguous); A per-wave in registers;
// MFMA 32x32x16, K=128. C/D: col=lane&31, row=(reg&3)+8*(reg>>2)+4*(lane>>5).
// Diagonal tile (j0==rbase, only when it==js) wave-uniform; self-pair excluded.
//
// Class block: masked S/T/CNT sums over 256 rows of qb (labels used as
// VALUES only -> poison-safe).
__global__ __launch_bounds__(512) void main_kernel(const short* __restrict__ qb,
                                                   const short* __restrict__ qb2,
                                                   const long long* __restrict__ y,
                                                   float* __restrict__ pse,
                                                   float* __restrict__ S) {
    int tid = threadIdx.x;
    int wave = tid >> 6;
    int lane = tid & 63;

    if (blockIdx.x >= GEMM_BLOCKS) {
        // ---- class-sum path (512 threads: 4 row-groups x 128 dims) ----
        __shared__ float shS[512];
        __shared__ float shT[8];
        __shared__ float shC[4];
        int cb = blockIdx.x - GEMM_BLOCKS;   // 0..159
        int c  = cb / CGRP;
        int g  = cb % CGRP;
        int d  = tid & 127;
        int rg = tid >> 7;                   // 0..3
        int r0 = g * CROWS + rg * (CROWS / 4);

        float sS = 0.f, sT = 0.f, cnt = 0.f;
        #pragma unroll 4
        for (int i = 0; i < CROWS / 4; ++i) {
            int r = r0 + i;
            bool m = ((int)y[r & 2047] == c);      // wave-uniform broadcast
            float q = bf2f(qb[r * D + d]);         // coalesced reads
            sS += m ? q : 0.f;
            sT += m ? q * q : 0.f;
            cnt += m ? 1.f : 0.f;
        }

        shS[tid] = sS;
        #pragma unroll
        for (int m = 1; m < 64; m <<= 1) sT += __shfl_xor(sT, m);
        if (lane == 0) shT[wave] = sT;
        if (d == 0) shC[rg] = cnt;
        __syncthreads();
        if (tid < 128)
            atomicAdd(&S[c * D + tid],
                      shS[tid] + shS[tid + 128] + shS[tid + 256] + shS[tid + 384]);
        if (tid == 0) {
            float t8 = 0.f;
            #pragma unroll
            for (int w = 0; w < 8; ++w) t8 += shT[w];
            atomicAdd(&S[NCLS * D + c], t8);                                  // T_c
            atomicAdd(&S[NCLS * D + NCLS + c], shC[0] + shC[1] + shC[2] + shC[3]); // CNT_c
        }
        return;
    }

    // ---- GEMM path: map linear block id -> upper-triangle (it, js) ----
    __shared__ short ldsB[BN * D];     // 64 KB
    __shared__ float colsum[BN];       // 1 KB (off-diag col-sums)
    int b = blockIdx.x, it = 0;
    while (b >= NIT - it) { b -= NIT - it; ++it; }
    int js = it + b;
    int col  = lane & 31;
    int half = lane >> 5;
    int rbase = it * BM + wave * 32;
    bool offdiag = (it != js);

    // stage the B-slice: 64KB contiguous in qb2, coalesced copy
    {
        const bf16x8* src = (const bf16x8*)(qb2 + js * (BN * D));
        bf16x8* dst = (bf16x8*)ldsB;
        #pragma unroll
        for (int i = 0; i < 8; ++i) dst[tid + 512 * i] = src[tid + 512 * i];
    }
    if (tid < BN) colsum[tid] = 0.f;

    // A fragments for this wave's 32 rows: lane-contiguous from qb2
    const short* ap = qb2 + ((rbase >> 5) * 4096) + lane * 8;
    bf16x8 af[8];
    #pragma unroll
    for (int k = 0; k < 8; ++k) af[k] = *(const bf16x8*)(ap + k * 512);

    float se[16];
    #pragma unroll
    for (int r = 0; r < 16; ++r) se[r] = 0.f;

    __syncthreads();                   // B staged, colsum zeroed

    const bf16x8* lb = (const bf16x8*)ldsB;
    #pragma unroll
    for (int t = 0; t < NT; ++t) {
        int j0 = js * BN + t * 32;

        floatx16 acc;
        #pragma unroll
        for (int r = 0; r < 16; ++r) acc[r] = 0.f;
        #pragma unroll
        for (int k = 0; k < 8; ++k)
            acc = __builtin_amdgcn_mfma_f32_32x32x16_bf16(
                af[k], lb[t * 512 + k * 64 + lane], acc, 0, 0, 0);

        if (j0 == rbase) {                    // wave-uniform: diagonal tile
            int jcol = j0 + col;
            #pragma unroll
            for (int r = 0; r < 16; ++r) {
                int rowr = rbase + (r & 3) + 8 * (r >> 2) + 4 * half;
                float e = __builtin_amdgcn_exp2f(acc[r] * E2SCALE);
                se[r] += (rowr == jcol) ? 0.f : e;
            }
        } else {
            float cs = 0.f;
            #pragma unroll
            for (int r = 0; r < 16; ++r) {
                float e = __builtin_amdgcn_exp2f(acc[r] * E2SCALE);
                se[r] += e;
                cs += e;
            }
            if (offdiag) {                    // col-sums for the mirrored tile
                cs += __shfl_xor(cs, 32);     // both halves: full 32-row sum
                if (half == 0) atomicAdd(&colsum[t * 32 + col], cs);
            }
        }
    }

    // row-sums: reduce over 32 cols, plain-store slice js for it-block rows
    #pragma unroll
    for (int r = 0; r < 16; ++r) {
        float a = se[r];
        #pragma unroll
        for (int m = 1; m < 32; m <<= 1) a += __shfl_xor(a, m);
        if (col == 0) {
            int rowr = rbase + (r & 3) + 8 * (r >> 2) + 4 * half;
            pse[rowr * NIT + js] = a;         // unique (row, js) writer
        }
    }

    // col-sums: slice it for js-block rows (mirrored half), plain store
    if (offdiag) {
        __syncthreads();                      // all waves' colsum adds done
        if (tid < BN)
            pse[(js * BN + tid) * NIT + it] = colsum[tid];   // unique writer
    }
}

// loss = (sum_i log(sum_k pse[i][k])  -  sum_c 10*(||S_c||^2 - T_c)/(n_c-1)) / N2
__global__ __launch_bounds__(512) void finish_kernel(const float* __restrict__ pse,
                                                     const float* __restrict__ S,
                                                     float* __restrict__ out) {
    __shared__ float red[16];
    int tid = threadIdx.x;
    int wave = tid >> 6;
    int lane = tid & 63;

    // denominator: sum 16 slice-partials per row (64B contiguous), log, reduce
    float L = 0.f;
    for (int r = tid; r < N2; r += 512) {
        float s = 0.f;
        #pragma unroll
        for (int k = 0; k < NIT; ++k) s += pse[r * NIT + k];
        L += __logf(s);
    }
    #pragma unroll
    for (int m = 1; m < 64; m <<= 1) L += __shfl_xor(L, m);

    // positive-pair term: wave w handles classes w and w+8
    float P = 0.f;
    for (int c = wave; c < NCLS; c += 8) {
        float2 sv = ((const float2*)(S + c * D))[lane];
        float s2 = sv.x * sv.x + sv.y * sv.y;
        #pragma unroll
        for (int m = 1; m < 64; m <<= 1) s2 += __shfl_xor(s2, m);
        float n = S[NCLS * D + NCLS + c];
        P += (n >= 2.0f) ? (s2 - S[NCLS * D + c]) * TAU_INV / (n - 1.0f) : 0.f;
    }

    if (lane == 0) { red[wave] = L; red[8 + wave] = P; }
    __syncthreads();
    if (tid == 0) {
        float Ls = 0.f, Ps = 0.f;
        #pragma unroll
        for (int w = 0; w < 8; ++w) { Ls += red[w]; Ps += red[8 + w]; }
        out[0] = (Ls - Ps) * (1.0f / (float)N2);
    }
}

extern "C" void kernel_launch(void* const* d_in, const int* in_sizes, int n_in,
                              void* d_out, int out_size, void* d_ws, size_t ws_size,
                              hipStream_t stream) {
    const float*     zi = (const float*)d_in[0];
    const float*     zj = (const float*)d_in[1];
    const long long* y  = (const long long*)d_in[2];
    float* out = (float*)d_out;

    char* ws = (char*)d_ws;
    short* qb   = (short*)ws;                                  // 1 MB row-major
    short* qb2  = qb + N2 * D;                                 // 1 MB chunk-major
    float* pse  = (float*)(ws + 2 * N2 * D * sizeof(short));   // 4096*16 f32 = 256 KB
    float* S    = pse + N2 * NIT;                              // 1300 f32: S/T/CNT

    prep_kernel<<<N2, 64, 0, stream>>>(zi, zj, qb, qb2, S);
    main_kernel<<<GEMM_BLOCKS + CB, 512, 0, stream>>>(qb, qb2, y, pse, S);
    finish_kernel<<<1, 512, 0, stream>>>(pse, S, out);
}